// Round 4
// baseline (609.518 us; speedup 1.0000x reference)
//
#include <hip/hip_runtime.h>
#include <math.h>

// B=128, N=4096, Din=128, D=128, S(slots)=8, H=256, 3 iterations.
// Algebraic folds: logits = xn @ q2^T with q2 = slots_n @ Wqk, Wqk = scale*Wq^T@Wk.
// gx = raw @ Wihv^T with raw = attn^T @ xn (per-chunk partials), Wihv = Wih@Wv.
// k/v never materialized; only ln_x (bf16, row-major) is stored.
// k_attn: tile staged to LDS once via global_load_lds(16B), XOR-swizzled:
//   16B chunk (r, seg) of a 64x256B tile stored at LDS slot r*16 + (seg ^ (r&15)).
//   -> A-frag ds_read_b128: 2-way bank aliasing (free); PV ds_read_b64: conflict-free.
// MFMA 16x16x32 bf16 layouts (verified):
//   C/D: col = lane&15, row = (lane>>4)*4 + reg
//   A  : A[m = lane&15][k = (lane>>4)*8 + j]
//   B  : B[k = (lane>>4)*8 + j][n = lane&15]  (row-major [N][K] source)

typedef __attribute__((ext_vector_type(4))) float fx4;
typedef __attribute__((ext_vector_type(8))) short sx8;
typedef __attribute__((ext_vector_type(8))) __bf16 bfx8;
typedef __attribute__((ext_vector_type(4))) unsigned short ux4;

static __device__ __forceinline__ fx4 MFMA(sx8 a, sx8 b, fx4 c) {
  return __builtin_amdgcn_mfma_f32_16x16x32_bf16(
      __builtin_bit_cast(bfx8, a), __builtin_bit_cast(bfx8, b), c, 0, 0, 0);
}

static __device__ __forceinline__ unsigned short f2bf(float f) {
  union { float f; unsigned u; } x; x.f = f;
  unsigned r = x.u + 0x7fffu + ((x.u >> 16) & 1u);  // RNE
  return (unsigned short)(r >> 16);
}
static __device__ __forceinline__ float bf2f(unsigned short u) {
  union { unsigned u; float f; } x; x.u = ((unsigned)u) << 16; return x.f;
}

typedef __attribute__((address_space(1))) const unsigned int gas_uint;
typedef __attribute__((address_space(3))) unsigned int las_uint;

// ---------------- fold: Wqk = scale*Wq^T@Wk, Wihv = Wih@Wv (fp32) ----------------
__global__ __launch_bounds__(256) void k_fold(
    const float* __restrict__ Wq, const float* __restrict__ Wk,
    const float* __restrict__ Wih, const float* __restrict__ Wv,
    float* __restrict__ Wqk, float* __restrict__ Wihv) {
  int idx = blockIdx.x * 256 + threadIdx.x;
  if (idx < 16384) {
    int e = idx >> 7, c = idx & 127;
    float s = 0.f;
#pragma unroll 4
    for (int d = 0; d < 128; d++) s += Wq[d * 128 + e] * Wk[d * 128 + c];
    Wqk[idx] = s * 0.08838834764831845f;
    return;
  }
  idx -= 16384;
  if (idx < 49152) {
    int g = idx >> 7, c = idx & 127;
    float s = 0.f;
#pragma unroll 4
    for (int d = 0; d < 128; d++) s += Wih[g * 128 + d] * Wv[d * 128 + c];
    Wihv[idx] = s;
  }
}

// ---------------- pack: slots init + bf16 weight tables ----------------
__global__ __launch_bounds__(256) void k_pack(
    const float* __restrict__ noise, const float* __restrict__ mu,
    const float* __restrict__ lsig, const float* __restrict__ Wqk,
    const float* __restrict__ Wihv, const float* __restrict__ Whh,
    const float* __restrict__ W1, const float* __restrict__ W2,
    float* __restrict__ slots, unsigned short* __restrict__ wqk_b,
    unsigned short* __restrict__ wihv_b, unsigned short* __restrict__ whh_b,
    unsigned short* __restrict__ w1_b, unsigned short* __restrict__ w2_b) {
  int idx = blockIdx.x * 256 + threadIdx.x;
  if (idx < 131072) {
    int d = idx & 127;
    slots[idx] = mu[d] + expf(lsig[d]) * noise[idx];
    return;
  }
  idx -= 131072;
  if (idx < 16384) {  // wqk_b row-major [n=c][k=e] <- Wqk[e,c]
    wqk_b[idx] = f2bf(Wqk[(idx & 127) * 128 + (idx >> 7)]);
    return;
  }
  idx -= 16384;
  if (idx < 49152) { wihv_b[idx] = f2bf(Wihv[idx]); return; }
  idx -= 49152;
  if (idx < 49152) { whh_b[idx] = f2bf(Whh[idx]); return; }
  idx -= 49152;
  if (idx < 32768) { w1_b[idx] = f2bf(W1[idx]); return; }
  idx -= 32768;
  w2_b[idx] = f2bf(W2[idx]);
}

// ---------------- LN(x) -> bf16 row-major, pure streaming ----------------
__global__ __launch_bounds__(256) void k_ln(
    const float* __restrict__ x, unsigned short* __restrict__ ln16) {
  long row = (long)blockIdx.x * 8 + (threadIdx.x >> 5);
  int c4 = (threadIdx.x & 31) * 4;
  fx4 t = *(const fx4*)(x + row * 128 + c4);
  float s = t.x + t.y + t.z + t.w;
  float s2 = t.x * t.x + t.y * t.y + t.z * t.z + t.w * t.w;
#pragma unroll
  for (int m = 1; m < 32; m <<= 1) {
    s += __shfl_xor(s, m, 64);
    s2 += __shfl_xor(s2, m, 64);
  }
  float mean = s * 0.0078125f;
  float rstd = rsqrtf(s2 * 0.0078125f - mean * mean + 1e-5f);
  ux4 o;
  o.x = f2bf((t.x - mean) * rstd);
  o.y = f2bf((t.y - mean) * rstd);
  o.z = f2bf((t.z - mean) * rstd);
  o.w = f2bf((t.w - mean) * rstd);
  *(ux4*)(ln16 + row * 128 + c4) = o;
}

// ---------------- iter0 only: LN(slots) + q2 = slots_n @ Wqk ----------------
__global__ __launch_bounds__(64) void k_slot_pre(
    const float* __restrict__ slots, const unsigned short* __restrict__ wqk_b,
    float* __restrict__ slots_n, unsigned short* __restrict__ q2_b) {
  __shared__ __align__(16) short xf[4 * 64 * 8];
  int l = threadIdx.x;
  int r = l & 15, seg = l >> 4;
  long rowbase = (long)blockIdx.x * 16;
  {
    const float* xp = slots + (rowbase + r) * 128 + seg * 32;
    float* snp = slots_n + (rowbase + r) * 128 + seg * 32;
    float v[32];
    float s = 0.f, s2 = 0.f;
#pragma unroll
    for (int i = 0; i < 8; i++) {
      fx4 t = *(const fx4*)(xp + i * 4);
      v[i * 4 + 0] = t.x; v[i * 4 + 1] = t.y; v[i * 4 + 2] = t.z; v[i * 4 + 3] = t.w;
      s += t.x + t.y + t.z + t.w;
      s2 += t.x * t.x + t.y * t.y + t.z * t.z + t.w * t.w;
    }
    s += __shfl_xor(s, 16, 64);  s += __shfl_xor(s, 32, 64);
    s2 += __shfl_xor(s2, 16, 64); s2 += __shfl_xor(s2, 32, 64);
    float mean = s * 0.0078125f;
    float rstd = rsqrtf(s2 * 0.0078125f - mean * mean + 1e-5f);
#pragma unroll
    for (int i = 0; i < 8; i++) {
      fx4 t = {(v[i * 4 + 0] - mean) * rstd, (v[i * 4 + 1] - mean) * rstd,
               (v[i * 4 + 2] - mean) * rstd, (v[i * 4 + 3] - mean) * rstd};
      *(fx4*)(snp + i * 4) = t;
      v[i * 4 + 0] = t.x; v[i * 4 + 1] = t.y; v[i * 4 + 2] = t.z; v[i * 4 + 3] = t.w;
    }
#pragma unroll
    for (int q = 0; q < 4; q++) {
      sx8 t;
#pragma unroll
      for (int j = 0; j < 8; j++) t[j] = (short)f2bf(v[q * 8 + j]);
      *(sx8*)&xf[(seg * 64 + (r + 16 * q)) * 8] = t;
    }
  }
  __syncthreads();
  const fx4 z4 = {0.f, 0.f, 0.f, 0.f};
  fx4 acc[8];
#pragma unroll
  for (int nt = 0; nt < 8; nt++) acc[nt] = z4;
#pragma unroll
  for (int ks = 0; ks < 4; ks++) {
    sx8 a = *(const sx8*)&xf[(ks * 64 + l) * 8];
#pragma unroll
    for (int nt = 0; nt < 8; nt++) {
      sx8 bfr = *(const sx8*)(wqk_b + (nt * 16 + (l & 15)) * 128 + ks * 32 + (l >> 4) * 8);
      acc[nt] = MFMA(a, bfr, acc[nt]);
    }
  }
  int cl = l & 15, rq = (l >> 4) * 4;
#pragma unroll
  for (int nt = 0; nt < 8; nt++)
#pragma unroll
    for (int rg = 0; rg < 4; rg++)
      q2_b[(rowbase + rq + rg) * 128 + nt * 16 + cl] = f2bf(acc[nt][rg]);
}

// ---------------- attention: LDS-staged single-pass tiles ----------------
// grid = 4096 blocks x 128 thr (2 waves); wave = one 64-row tile; block = chunk of 128 rows.
__global__ __launch_bounds__(128) void k_attn(
    const unsigned short* __restrict__ ln16, const unsigned short* __restrict__ q2b,
    float* __restrict__ upd_part, float* __restrict__ sattn_part) {
  __shared__ __align__(16) char smem[40960];
  // [0,32768): two 16KB swizzled tiles; [32768,40960): two 4KB attn/upd buffers
  int tid = threadIdx.x, w = tid >> 6, l = tid & 63;
  int b = blockIdx.x >> 5, p = blockIdx.x & 31;
  int tile = p * 2 + w;  // [0,64) within batch
  const unsigned short* tg = ln16 + ((size_t)b * 4096 + tile * 64) * 128;
  unsigned short* tl = (unsigned short*)(smem + w * 16384);
  float* attnw = (float*)(smem + 32768 + w * 4096);
  int hi = l >> 4, s = l & 15;
  // 1) deep prefetch: 16 x global_load_lds(16B/lane), XOR-swizzled placement
#pragma unroll
  for (int i = 0; i < 16; i++) {
    int r = i * 4 + hi;
    int gchunk = r * 16 + (s ^ (r & 15));
    __builtin_amdgcn_global_load_lds((gas_uint*)(tg + gchunk * 8),
                                     (las_uint*)(tl + i * 512), 16, 0, 0);
  }
  // 2) q2 B-frags (slots 0..7, zero-pad 8..15)
  sx8 qf[4];
#pragma unroll
  for (int ks = 0; ks < 4; ks++) {
    if (s < 8) {
      qf[ks] = *(const sx8*)(q2b + ((long)b * 8 + s) * 128 + ks * 32 + hi * 8);
    } else {
      sx8 t;
#pragma unroll
      for (int j = 0; j < 8; j++) t[j] = 0;
      qf[ks] = t;
    }
  }
  __builtin_amdgcn_s_waitcnt(0);
  __syncthreads();
  // 3) logits via MFMA + softmax (per-s over 8 lanes)
  const fx4 z4 = {0.f, 0.f, 0.f, 0.f};
  float sat_loc = 0.f;
#pragma unroll
  for (int mt = 0; mt < 4; mt++) {
    fx4 cc = z4;
#pragma unroll
    for (int ks = 0; ks < 4; ks++) {
      int r = mt * 16 + s;
      int slot = r * 16 + ((ks * 4 + hi) ^ s);
      sx8 a = *(const sx8*)(tl + slot * 8);
      cc = MFMA(a, qf[ks], cc);
    }
#pragma unroll
    for (int rg = 0; rg < 4; rg++) {
      float lg = cc[rg];
      float mx = lg;
      mx = fmaxf(mx, __shfl_xor(mx, 1, 64));
      mx = fmaxf(mx, __shfl_xor(mx, 2, 64));
      mx = fmaxf(mx, __shfl_xor(mx, 4, 64));
      float pp = __expf(lg - mx);
      float sm = pp;
      sm += __shfl_xor(sm, 1, 64);
      sm += __shfl_xor(sm, 2, 64);
      sm += __shfl_xor(sm, 4, 64);
      float at = pp / sm + 1e-8f;
      if (s < 8) sat_loc += at;
      attnw[(mt * 16 + hi * 4 + rg) * 16 + s] = at;
    }
  }
  // 4) PV from LDS (single pass over tile)
  float ua[4][4] = {};
  int d0 = (l & 31) * 4, s0 = (l >> 5) * 4;
  int segp = (l & 31) >> 1, intra = (l & 1) * 4;  // halfword offset within 16B chunk
#pragma unroll 2
  for (int n0 = 0; n0 < 64; n0 += 8) {
    ux4 vv[8]; fx4 at4[8];
#pragma unroll
    for (int u = 0; u < 8; u++) {
      int n = n0 + u;
      int slot = n * 16 + (segp ^ (n & 15));
      vv[u] = *(const ux4*)(tl + slot * 8 + intra);
      at4[u] = *(const fx4*)&attnw[n * 16 + s0];
    }
#pragma unroll
    for (int u = 0; u < 8; u++) {
      float v0 = bf2f(vv[u].x), v1 = bf2f(vv[u].y), v2 = bf2f(vv[u].z), v3 = bf2f(vv[u].w);
#pragma unroll
      for (int si = 0; si < 4; si++) {
        float av = at4[u][si];
        ua[si][0] += av * v0; ua[si][1] += av * v1;
        ua[si][2] += av * v2; ua[si][3] += av * v3;
      }
    }
  }
  // 5) per-wave update (8x128) into attnw overlay; sat into dead tile region
#pragma unroll
  for (int si = 0; si < 4; si++) {
    fx4 tv = {ua[si][0], ua[si][1], ua[si][2], ua[si][3]};
    *(fx4*)&attnw[(s0 + si) * 128 + d0] = tv;
  }
  sat_loc += __shfl_xor(sat_loc, 16, 64);
  sat_loc += __shfl_xor(sat_loc, 32, 64);
  if (l < 8) ((float*)tl)[l] = sat_loc;
  __syncthreads();
  // 6) combine 2 waves -> chunk b*32+p
  {
    int chunk = b * 32 + p;
    const float* a0 = (const float*)(smem + 32768);
    const float* a1 = (const float*)(smem + 32768 + 4096);
    int i = tid * 8;
    fx4 o0 = *(const fx4*)&a0[i] + *(const fx4*)&a1[i];
    fx4 o1 = *(const fx4*)&a0[i + 4] + *(const fx4*)&a1[i + 4];
    *(fx4*)(upd_part + (size_t)chunk * 1024 + i) = o0;
    *(fx4*)(upd_part + (size_t)chunk * 1024 + i + 4) = o1;
    if (tid < 8) {
      const float* s0b = (const float*)smem;
      const float* s1b = (const float*)(smem + 16384);
      sattn_part[chunk * 8 + tid] = s0b[tid] + s1b[tid];
    }
  }
}

// ---------------- GRU + MLP (+ fused next-iter LN+q2), 1 batch (8 rows) per block ----------
__global__ __launch_bounds__(256) void k_slot_post(
    const float* __restrict__ upd_part, const float* __restrict__ sattn_part,
    float* __restrict__ slots_n,
    const unsigned short* __restrict__ wihv_b, const unsigned short* __restrict__ whh_b,
    const float* __restrict__ b_ih, const float* __restrict__ b_hh,
    const unsigned short* __restrict__ w1_b, const float* __restrict__ b1,
    const unsigned short* __restrict__ w2_b, const float* __restrict__ b2,
    const unsigned short* __restrict__ wqk_b,
    unsigned short* __restrict__ q2_b, float* __restrict__ out_final, int final_flag) {
  __shared__ __align__(16) char smem[78336];
  float* gx = (float*)smem;                  // 16x384 fp32 = 24576
  float* gh = (float*)(smem + 24576);        // 24576
  float* xred = gx;                          // overlay: 4 waves x 1024 floats
  short* xfr = (short*)(smem + 49152);       // 4096
  short* hfr = (short*)(smem + 53248);       // 4096
  short* ynf = (short*)(smem + 57344);       // 4096
  short* y1f = (short*)(smem + 61440);       // 8192
  float* snew = (float*)(smem + 69632);      // 16*132*4 = 8448
  float* satred = (float*)(smem + 78080);    // 32 floats
  int tid = threadIdx.x, w = tid >> 6, l = tid & 63;
  int bb = blockIdx.x;  // batch
  int rowbase = bb * 8;
  int r = l & 15, seg = l >> 4;
  {  // phase A: wave w reduces chunks w*8..w*8+7 of this batch
    int r8 = l & 7, h8 = l >> 3;
    float a[16];
#pragma unroll
    for (int i = 0; i < 16; i++) a[i] = 0.f;
    float satsum = 0.f;
#pragma unroll
    for (int ci = 0; ci < 8; ci++) {
      int ch = bb * 32 + w * 8 + ci;
      const float* up = upd_part + (size_t)ch * 1024 + r8 * 128 + h8 * 16;
#pragma unroll
      for (int i = 0; i < 4; i++) {
        fx4 t = *(const fx4*)(up + i * 4);
        a[i * 4 + 0] += t.x; a[i * 4 + 1] += t.y;
        a[i * 4 + 2] += t.z; a[i * 4 + 3] += t.w;
      }
      if (h8 == 0) satsum += sattn_part[ch * 8 + r8];
    }
#pragma unroll
    for (int i = 0; i < 4; i++) {
      fx4 t = {a[i * 4], a[i * 4 + 1], a[i * 4 + 2], a[i * 4 + 3]};
      *(fx4*)&xred[w * 1024 + r8 * 128 + h8 * 16 + i * 4] = t;
    }
    if (h8 == 0) satred[w * 8 + r8] = satsum;
  }
  __syncthreads();
  if (w == 0) {  // combine -> x A-frags (rows m<8 valid, zero-pad 8..15)
    float a[32];
    if (r < 8) {
      float inv = 1.f / (satred[r] + satred[8 + r] + satred[16 + r] + satred[24 + r]);
#pragma unroll
      for (int i = 0; i < 8; i++) {
        fx4 t = *(const fx4*)&xred[r * 128 + seg * 32 + i * 4];
        fx4 t1 = *(const fx4*)&xred[1024 + r * 128 + seg * 32 + i * 4];
        fx4 t2 = *(const fx4*)&xred[2048 + r * 128 + seg * 32 + i * 4];
        fx4 t3 = *(const fx4*)&xred[3072 + r * 128 + seg * 32 + i * 4];
        t = t + t1 + t2 + t3;
        a[i * 4 + 0] = t.x * inv; a[i * 4 + 1] = t.y * inv;
        a[i * 4 + 2] = t.z * inv; a[i * 4 + 3] = t.w * inv;
      }
    } else {
#pragma unroll
      for (int i = 0; i < 32; i++) a[i] = 0.f;
    }
#pragma unroll
    for (int q = 0; q < 4; q++) {
      sx8 t;
#pragma unroll
      for (int j = 0; j < 8; j++) t[j] = (short)f2bf(a[q * 8 + j]);
      *(sx8*)&xfr[(seg * 64 + (r + 16 * q)) * 8] = t;
    }
  } else if (w == 1) {  // h A-frags (rows<8 valid)
#pragma unroll
    for (int q = 0; q < 4; q++) {
      sx8 t;
      if (r < 8) {
        const float* hp = slots_n + (long)(rowbase + r) * 128 + seg * 32;
        fx4 t0 = *(const fx4*)(hp + q * 8);
        fx4 t1 = *(const fx4*)(hp + q * 8 + 4);
        t[0] = (short)f2bf(t0.x); t[1] = (short)f2bf(t0.y);
        t[2] = (short)f2bf(t0.z); t[3] = (short)f2bf(t0.w);
        t[4] = (short)f2bf(t1.x); t[5] = (short)f2bf(t1.y);
        t[6] = (short)f2bf(t1.z); t[7] = (short)f2bf(t1.w);
      } else {
#pragma unroll
        for (int j = 0; j < 8; j++) t[j] = 0;
      }
      *(sx8*)&hfr[(seg * 64 + (r + 16 * q)) * 8] = t;
    }
  }
  __syncthreads();
  const fx4 z4 = {0.f, 0.f, 0.f, 0.f};
  {  // GEMM1: gx = raw_scaled@Wihv^T, gh = h@Whh^T (N=384)
    fx4 ax[6], ah[6];
#pragma unroll
    for (int j = 0; j < 6; j++) { ax[j] = z4; ah[j] = z4; }
#pragma unroll
    for (int ks = 0; ks < 4; ks++) {
      sx8 a_x = *(const sx8*)&xfr[(ks * 64 + l) * 8];
      sx8 a_h = *(const sx8*)&hfr[(ks * 64 + l) * 8];
#pragma unroll
      for (int j = 0; j < 6; j++) {
        int nt = w * 6 + j;
        sx8 bx = *(const sx8*)(wihv_b + (nt * 16 + (l & 15)) * 128 + ks * 32 + (l >> 4) * 8);
        sx8 bh = *(const sx8*)(whh_b + (nt * 16 + (l & 15)) * 128 + ks * 32 + (l >> 4) * 8);
        ax[j] = MFMA(a_x, bx, ax[j]);
        ah[j] = MFMA(a_h, bh, ah[j]);
      }
    }
#pragma unroll
    for (int j = 0; j < 6; j++) {
      int col = (w * 6 + j) * 16 + (l & 15);
#pragma unroll
      for (int rg = 0; rg < 4; rg++) {
        int row = (l >> 4) * 4 + rg;
        gx[row * 384 + col] = ax[j][rg];
        gh[row * 384 + col] = ah[j][rg];
      }
    }
  }
  __syncthreads();
  {  // GRU gates (rows<8)
    int row = tid >> 4, j0 = (tid & 15) * 8;
    if (row < 8) {
#pragma unroll
      for (int j = j0; j < j0 + 8; j++) {
        float xr = gx[row * 384 + j] + b_ih[j];
        float xz = gx[row * 384 + 128 + j] + b_ih[128 + j];
        float xn = gx[row * 384 + 256 + j] + b_ih[256 + j];
        float hr = gh[row * 384 + j] + b_hh[j];
        float hz = gh[row * 384 + 128 + j] + b_hh[128 + j];
        float hn = gh[row * 384 + 256 + j] + b_hh[256 + j];
        float rr = 1.f / (1.f + __expf(-(xr + hr)));
        float zz = 1.f / (1.f + __expf(-(xz + hz)));
        float nn = tanhf(xn + rr * hn);
        float h = slots_n[(long)(rowbase + row) * 128 + j];
        snew[row * 132 + j] = (1.f - zz) * nn + zz * h;
      }
    }
  }
  __syncthreads();
  if (w == 0) {  // LN(snew) -> ynf A-frags (rows<8)
    float v[32];
    float s = 0.f, s2 = 0.f;
#pragma unroll
    for (int i = 0; i < 32; i++) {
      float t = (r < 8) ? snew[r * 132 + seg * 32 + i] : 0.f;
      v[i] = t; s += t; s2 += t * t;
    }
    s += __shfl_xor(s, 16, 64);  s += __shfl_xor(s, 32, 64);
    s2 += __shfl_xor(s2, 16, 64); s2 += __shfl_xor(s2, 32, 64);
    float mean = s * 0.0078125f;
    float rstd = rsqrtf(s2 * 0.0078125f - mean * mean + 1e-5f);
#pragma unroll
    for (int q = 0; q < 4; q++) {
      sx8 t;
#pragma unroll
      for (int j = 0; j < 8; j++) t[j] = (short)f2bf((v[q * 8 + j] - mean) * rstd);
      *(sx8*)&ynf[(seg * 64 + (r + 16 * q)) * 8] = t;
    }
  }
  __syncthreads();
  {  // GEMM2: y1 = relu(LN@W1^T + b1) -> A-frags for GEMM3
    fx4 y[4];
#pragma unroll
    for (int j = 0; j < 4; j++) y[j] = z4;
#pragma unroll
    for (int ks = 0; ks < 4; ks++) {
      sx8 a = *(const sx8*)&ynf[(ks * 64 + l) * 8];
#pragma unroll
      for (int j = 0; j < 4; j++) {
        int nt = w * 4 + j;
        sx8 bf = *(const sx8*)(w1_b + (nt * 16 + (l & 15)) * 128 + ks * 32 + (l >> 4) * 8);
        y[j] = MFMA(a, bf, y[j]);
      }
    }
#pragma unroll
    for (int j = 0; j < 4; j++) {
      int col = (w * 4 + j) * 16 + (l & 15);
      float bias = b1[col];
      int ks3 = col >> 5, qq = (col >> 3) & 3, jj = col & 7;
#pragma unroll
      for (int rg = 0; rg < 4; rg++) {
        float val = fmaxf(y[j][rg] + bias, 0.f);
        int m = (l >> 4) * 4 + rg;
        y1f[(ks3 * 64 + m + 16 * qq) * 8 + jj] = (short)f2bf(val);
      }
    }
  }
  __syncthreads();
  {  // GEMM3: snew += y1@W2^T + b2
    fx4 zz2[2];
    zz2[0] = z4; zz2[1] = z4;
#pragma unroll
    for (int ks = 0; ks < 8; ks++) {
      sx8 a = *(const sx8*)&y1f[(ks * 64 + l) * 8];
#pragma unroll
      for (int j = 0; j < 2; j++) {
        sx8 bf = *(const sx8*)(w2_b + ((w * 2 + j) * 16 + (l & 15)) * 256 + ks * 32 + (l >> 4) * 8);
        zz2[j] = MFMA(a, bf, zz2[j]);
      }
    }
#pragma unroll
    for (int j = 0; j < 2; j++) {
      int col = (w * 2 + j) * 16 + (l & 15);
      float bias = b2[col];
#pragma unroll
      for (int rg = 0; rg < 4; rg++) {
        int row = (l >> 4) * 4 + rg;
        snew[row * 132 + col] += zz2[j][rg] + bias;
      }
    }
  }
  __syncthreads();
  if (final_flag) {
    int row = tid >> 4, c8 = (tid & 15) * 8;
    if (row < 8) {
      fx4 t0 = *(const fx4*)&snew[row * 132 + c8];
      fx4 t1 = *(const fx4*)&snew[row * 132 + c8 + 4];
      *(fx4*)(out_final + (long)(rowbase + row) * 128 + c8) = t0;
      *(fx4*)(out_final + (long)(rowbase + row) * 128 + c8 + 4) = t1;
    }
    return;
  }
  // fused next-iter: LN(new slots) -> slots_n + q2
  if (w == 0) {
    float v[32];
    float s = 0.f, s2 = 0.f;
#pragma unroll
    for (int i = 0; i < 32; i++) {
      float t = (r < 8) ? snew[r * 132 + seg * 32 + i] : 0.f;
      v[i] = t; s += t; s2 += t * t;
    }
    s += __shfl_xor(s, 16, 64);  s += __shfl_xor(s, 32, 64);
    s2 += __shfl_xor(s2, 16, 64); s2 += __shfl_xor(s2, 32, 64);
    float mean = s * 0.0078125f;
    float rstd = rsqrtf(s2 * 0.0078125f - mean * mean + 1e-5f);
#pragma unroll
    for (int i = 0; i < 8; i++) {
      fx4 t = {(v[i * 4 + 0] - mean) * rstd, (v[i * 4 + 1] - mean) * rstd,
               (v[i * 4 + 2] - mean) * rstd, (v[i * 4 + 3] - mean) * rstd};
      if (r < 8) *(fx4*)(slots_n + (long)(rowbase + r) * 128 + seg * 32 + i * 4) = t;
      v[i * 4 + 0] = t.x; v[i * 4 + 1] = t.y; v[i * 4 + 2] = t.z; v[i * 4 + 3] = t.w;
    }
#pragma unroll
    for (int q = 0; q < 4; q++) {
      sx8 t;
#pragma unroll
      for (int j = 0; j < 8; j++) t[j] = (short)f2bf(v[q * 8 + j]);
      *(sx8*)&ynf[(seg * 64 + (r + 16 * q)) * 8] = t;
    }
  }
  __syncthreads();
  {  // q2 GEMM: wave w computes nt = w*2, w*2+1
    fx4 acc2[2];
    acc2[0] = z4; acc2[1] = z4;
#pragma unroll
    for (int ks = 0; ks < 4; ks++) {
      sx8 a = *(const sx8*)&ynf[(ks * 64 + l) * 8];
#pragma unroll
      for (int j = 0; j < 2; j++) {
        int nt = w * 2 + j;
        sx8 bf = *(const sx8*)(wqk_b + (nt * 16 + (l & 15)) * 128 + ks * 32 + (l >> 4) * 8);
        acc2[j] = MFMA(a, bf, acc2[j]);
      }
    }
    int cl = l & 15, rq = (l >> 4) * 4;
    if (rq < 8) {
#pragma unroll
      for (int j = 0; j < 2; j++) {
        int nt = w * 2 + j;
#pragma unroll
        for (int rg = 0; rg < 4; rg++)
          q2_b[(long)(rowbase + rq + rg) * 128 + nt * 16 + cl] = f2bf(acc2[j][rg]);
      }
    }
  }
}

extern "C" void kernel_launch(void* const* d_in, const int* in_sizes, int n_in,
                              void* d_out, int out_size, void* d_ws, size_t ws_size,
                              hipStream_t stream) {
  (void)in_sizes; (void)n_in; (void)out_size; (void)ws_size;
  const float* x = (const float*)d_in[0];
  const float* noise = (const float*)d_in[1];
  const float* mu = (const float*)d_in[2];
  const float* lsig = (const float*)d_in[3];
  const float* Wq = (const float*)d_in[4];
  const float* Wk = (const float*)d_in[5];
  const float* Wv = (const float*)d_in[6];
  const float* Wih = (const float*)d_in[7];
  const float* Whh = (const float*)d_in[8];
  const float* b_ih = (const float*)d_in[9];
  const float* b_hh = (const float*)d_in[10];
  const float* W1 = (const float*)d_in[11];
  const float* b1 = (const float*)d_in[12];
  const float* W2 = (const float*)d_in[13];
  const float* b2 = (const float*)d_in[14];

  char* ws = (char*)d_ws;
  size_t off = 0;
  auto take = [&](size_t bytes) {
    char* p = ws + off;
    off += (bytes + 255) & ~(size_t)255;
    return p;
  };
  unsigned short* ln16 = (unsigned short*)take(134217728);  // LN(x) bf16 row-major
  float* Wqk = (float*)take(65536);
  float* Wihv = (float*)take(196608);
  unsigned short* wqk_b = (unsigned short*)take(32768);
  unsigned short* wihv_b = (unsigned short*)take(98304);
  unsigned short* whh_b = (unsigned short*)take(98304);
  unsigned short* w1_b = (unsigned short*)take(65536);
  unsigned short* w2_b = (unsigned short*)take(65536);
  float* slots = (float*)take(524288);
  float* slots_n = (float*)take(524288);
  unsigned short* q2_b = (unsigned short*)take(262144);
  float* upd_part = (float*)take(16777216);   // (B,32,8,128) fp32
  float* sattn_part = (float*)take(131072);   // (B,32,8)

  k_fold<<<256, 256, 0, stream>>>(Wq, Wk, Wih, Wv, Wqk, Wihv);
  k_pack<<<1216, 256, 0, stream>>>(noise, mu, lsig, Wqk, Wihv, Whh, W1, W2,
                                   slots, wqk_b, wihv_b, whh_b, w1_b, w2_b);
  k_ln<<<65536, 256, 0, stream>>>(x, ln16);
  k_slot_pre<<<64, 64, 0, stream>>>(slots, wqk_b, slots_n, q2_b);
  for (int it = 0; it < 3; it++) {
    k_attn<<<4096, 128, 0, stream>>>(ln16, q2_b, upd_part, sattn_part);
    k_slot_post<<<128, 256, 0, stream>>>(upd_part, sattn_part, slots_n, wihv_b, whh_b,
                                         b_ih, b_hh, w1_b, b1, w2_b, b2, wqk_b,
                                         q2_b, (float*)d_out, (it == 2) ? 1 : 0);
  }
}